// Round 5
// baseline (249.336 us; speedup 1.0000x reference)
//
#include <hip/hip_runtime.h>
#include <hip/hip_bf16.h>
#include <math.h>

#define BB 8
#define NN 128
#define HN 256
#define HE 128
#define NH 8
#define DH 32
#define PP 8128
#define BP (BB*PP)   // 65024

typedef __hip_bfloat16 bf16;
typedef __hip_bfloat162 bf162;
typedef __attribute__((ext_vector_type(8))) short bf16x8;
typedef __attribute__((ext_vector_type(4))) float f32x4;

__device__ __forceinline__ float bf2f(bf16 x){ return __bfloat162float(x); }
__device__ __forceinline__ float bfraw2f(short u){
  return __uint_as_float(((unsigned)(unsigned short)u) << 16);
}

__device__ __forceinline__ float wave_sum(float v){
  #pragma unroll
  for (int off=32; off>=1; off>>=1) v += __shfl_xor(v, off, 64);
  return v;
}
__device__ __forceinline__ float wave_max(float v){
  #pragma unroll
  for (int off=32; off>=1; off>>=1) v = fmaxf(v, __shfl_xor(v, off, 64));
  return v;
}
__device__ __forceinline__ float g16_sum(float v){
  #pragma unroll
  for (int off=8; off>=1; off>>=1) v += __shfl_xor(v, off, 16);
  return v;
}

// triu pair index for N=128, i<j: p = i*(255-i)/2 + (j-i-1)
__device__ __forceinline__ int pair_idx(int a, int c){
  int i = a < c ? a : c;
  int j = a < c ? c : a;
  return ((i*(255 - i))>>1) + (j - i - 1);
}

// ---- canonical fp32 workspace layout (float offsets). edge_feat NOT converted. ----
#define C_NODE 0LL
#define C_MASK 262144LL
#define C_WQKV 327168LL
#define C_BQKV 523776LL
#define C_WEV  524544LL
#define C_BEV  557312LL
#define C_WEA  557568LL
#define C_BEA  558592LL
#define C_WO   558600LL
#define C_BO   689672LL
#define C_WSK  689928LL
#define C_BSK  821000LL
#define C_GN   821512LL
#define C_BN   821768LL
#define C_GE   822024LL
#define C_BE   822152LL
#define IOFF   822400LL
#define TOT8   102785
#define CONVBLKS 402          // ceil(TOT8/256)
// intermediates (float offsets from IOFF)
#define I_NIN  0LL
#define I_Q    262144LL
#define I_K    524288LL
#define I_V    786432LL
#define I_ATTN 1048576LL
#define I_EA2  1310720LL   // [64][PP] f32 = 520192
#define I_XG   1830912LL   // [BP][128] bf16 = 4161536 float-slots
#define I_EVAL 5992448LL   // [64][PP][32] bf16 = 8323072 float-slots
#define I_WT   14315520LL  // [256][128] bf16 = 16384 float-slots
#define I_FLG  14331904LL

// ---------------- Converter + Wev transpose + dtype detect ----------------
struct SrcPtrs { const void* p[16]; };

__global__ __launch_bounds__(256) void k_convert(SrcPtrs sp, float* __restrict__ dst,
                                                 int* __restrict__ flags,
                                                 const unsigned short* __restrict__ nodeRaw,
                                                 const void* __restrict__ rawWev,
                                                 bf16* __restrict__ Wt)
{
  __shared__ int sbad;
  if (threadIdx.x == 0) sbad = 0;
  __syncthreads();
  {
    int bad = 0;
    for (int i = threadIdx.x; i < 1024; i += 256){
      unsigned e = (nodeRaw[i] >> 7) & 0xFFu;
      if (e >= 194u) bad = 1;
    }
    if (bad) sbad = 1;
  }
  __syncthreads();
  const int f32 = sbad;        // 1 = inputs fp32, 0 = bf16
  if (blockIdx.x == 0 && threadIdx.x == 0) flags[0] = f32;

  if (blockIdx.x >= CONVBLKS){
    // Wev transpose from RAW input: idx over [128][256] -> Wt [256][128] bf16
    int idx = (blockIdx.x - CONVBLKS)*256 + threadIdx.x;   // < 32768
    float v = f32 ? ((const float*)rawWev)[idx]
                  : bfraw2f(((const short*)rawWev)[idx]);
    Wt[(idx & 255)*128 + (idx >> 8)] = __float2bfloat16(v);
    return;
  }

  int o = blockIdx.x*256 + threadIdx.x;
  if (o >= TOT8) return;
  const int cum[17] = {0,32768,40896,65472,65568,69664,69696,69824,69825,
                       86209,86241,102625,102689,102721,102753,102769,102785};
  int s = 0;
  #pragma unroll
  for (int i = 1; i <= 15; i++) if (o >= cum[i]) s = i;
  const int li = o - cum[s];
  float4 r0, r1;
  if (f32){
    const float4* src = (const float4*)sp.p[s];
    r0 = src[2*li]; r1 = src[2*li+1];
  } else {
    union { float4 f; unsigned short u[8]; } cv;
    cv.f = ((const float4*)sp.p[s])[li];
    r0.x = __uint_as_float((unsigned)cv.u[0] << 16);
    r0.y = __uint_as_float((unsigned)cv.u[1] << 16);
    r0.z = __uint_as_float((unsigned)cv.u[2] << 16);
    r0.w = __uint_as_float((unsigned)cv.u[3] << 16);
    r1.x = __uint_as_float((unsigned)cv.u[4] << 16);
    r1.y = __uint_as_float((unsigned)cv.u[5] << 16);
    r1.z = __uint_as_float((unsigned)cv.u[6] << 16);
    r1.w = __uint_as_float((unsigned)cv.u[7] << 16);
  }
  float4* d = (float4*)(dst + (long long)cum[s]*8);
  d[2*li]   = r0;
  d[2*li+1] = r1;
}

// ---------------- Kernel 1: node LN + QKV GEMM ----------------
__global__ __launch_bounds__(256) void k1_node_ln_qkv(
    const float* __restrict__ cnode, const float* __restrict__ cWqkv,
    const float* __restrict__ cbqkv, const float* __restrict__ cgn, const float* __restrict__ cbn,
    float* __restrict__ nin_ws, float* __restrict__ q_ws, float* __restrict__ k_ws,
    float* __restrict__ v_ws)
{
  __shared__ float xln[4][HN];
  const int t = threadIdx.x, wv = t>>6, lane = t&63;
  const int g0 = blockIdx.x*4;
  {
    int g = g0 + wv;
    float x[4];
    #pragma unroll
    for (int i=0;i<4;i++) x[i] = cnode[g*HN + lane + 64*i];
    float s = x[0]+x[1]+x[2]+x[3];
    s = wave_sum(s);
    float m = s * (1.0f/HN);
    float q = 0.f;
    #pragma unroll
    for (int i=0;i<4;i++){ float d = x[i]-m; q += d*d; }
    q = wave_sum(q);
    float rstd = rsqrtf(fmaxf(q*(1.0f/HN), 0.f) + 1e-5f);
    #pragma unroll
    for (int i=0;i<4;i++){
      int c = lane + 64*i;
      float y = (x[i]-m)*rstd*cgn[c] + cbn[c];
      xln[wv][c] = y;
      nin_ws[g*HN + c] = y;
    }
  }
  __syncthreads();
  float acc[4][3];
  #pragma unroll
  for (int c=0;c<3;c++){
    float bb = cbqkv[t + 256*c];
    #pragma unroll
    for (int r=0;r<4;r++) acc[r][c] = bb;
  }
  for (int k=0;k<HN;k+=4){
    float4 xv[4];
    #pragma unroll
    for (int r=0;r<4;r++) xv[r] = *reinterpret_cast<const float4*>(&xln[r][k]);
    #pragma unroll
    for (int kk=0;kk<4;kk++){
      float w0 = cWqkv[(k+kk)*768 + t];
      float w1 = cWqkv[(k+kk)*768 + t + 256];
      float w2 = cWqkv[(k+kk)*768 + t + 512];
      #pragma unroll
      for (int r=0;r<4;r++){
        float xr = (&xv[r].x)[kk];
        acc[r][0] = fmaf(xr, w0, acc[r][0]);
        acc[r][1] = fmaf(xr, w1, acc[r][1]);
        acc[r][2] = fmaf(xr, w2, acc[r][2]);
      }
    }
  }
  const int h = t>>5, d = t&31;
  #pragma unroll
  for (int r=0;r<4;r++){
    int g = g0 + r;
    int b = g>>7, n = g&127;
    int o = ((b*NH + h)*NN + n)*DH + d;
    q_ws[o] = acc[r][0]; k_ws[o] = acc[r][1]; v_ws[o] = acc[r][2];
  }
}

// ---------------- k2a: edge LN -> xg (bf16), Wea GEMM + mask fold -> ea2 ----------
// grid 4064 (16 rows/block), block 256
__global__ __launch_bounds__(256) void k2a_edge_ln(
    const void* __restrict__ edge_raw, const float* __restrict__ cWea,
    const float* __restrict__ cbea, const float* __restrict__ cge,
    const float* __restrict__ cbe, const float* __restrict__ cmask,
    bf16* __restrict__ xg, float* __restrict__ ea2, const int* __restrict__ flags)
{
  __shared__ float xlnS[16][136];
  __shared__ float part[128];
  const int t = threadIdx.x;
  const int R0 = blockIdx.x*16;
  const int b = R0 / PP;
  const int p0 = R0 - b*PP;
  const int f32 = flags[0];
  {
    int r = t>>4, sub = t&15;
    long base = (long)(R0 + r)*HE + sub*8;
    float x[8];
    if (f32){
      const float* cef = (const float*)edge_raw + base;
      float4 a0 = *reinterpret_cast<const float4*>(cef);
      float4 a1 = *reinterpret_cast<const float4*>(cef + 4);
      x[0]=a0.x; x[1]=a0.y; x[2]=a0.z; x[3]=a0.w;
      x[4]=a1.x; x[5]=a1.y; x[6]=a1.z; x[7]=a1.w;
    } else {
      union { float4 f; short u[8]; } cv;
      cv.f = *reinterpret_cast<const float4*>((const bf16*)edge_raw + base);
      #pragma unroll
      for (int i=0;i<8;i++) x[i] = bfraw2f(cv.u[i]);
    }
    float s = 0.f;
    #pragma unroll
    for (int i=0;i<8;i++) s += x[i];
    s = g16_sum(s);
    float m = s*(1.0f/HE);
    float q = 0.f;
    #pragma unroll
    for (int i=0;i<8;i++){ float dd = x[i]-m; q += dd*dd; }
    q = g16_sum(q);
    float rstd = rsqrtf(fmaxf(q*(1.0f/HE), 0.f) + 1e-5f);
    #pragma unroll
    for (int i=0;i<8;i++){
      int c = sub*8 + i;
      xlnS[r][c] = (x[i]-m)*rstd*cge[c] + cbe[c];
    }
  }
  __syncthreads();
  // write xg: thread -> row = t>>4, 8 consecutive cols
  {
    int r = t>>4, c0 = (t&15)*8;
    union { float4 f; bf16 h[8]; } o;
    #pragma unroll
    for (int i=0;i<8;i++) o.h[i] = __float2bfloat16(xlnS[r][c0+i]);
    *reinterpret_cast<float4*>(xg + (long)(R0 + r)*HE + c0) = o.f;
  }
  // e_adj (+mask fold): all 256 threads; (r,c) with k-range split by half
  {
    const int c = t & 7, r = (t>>3) & 15, half = t>>7;
    const int pid = r*8 + c;
    float s = half ? 0.0f : cbea[c];
    const int k0 = half*64;
    #pragma unroll 8
    for (int k=k0; k<k0+64; k++) s = fmaf(xlnS[r][k], cWea[k*NH + c], s);
    if (half){ part[pid] = s; }
    __syncthreads();
    if (!half){
      s += part[pid];
      int p = p0 + r;
      float mk = cmask[b*PP + p];
      ea2[(b*NH + c)*PP + p] = (mk != 0.0f) ? s : -9e15f;
    }
  }
}

// ---------------- k2b: MFMA GEMM e_val = xg @ Wev + bev -> [b][h][p][32] bf16 ----
// grid 1016 = 8 b x 127 rowblocks; block 256. 64 rows x 256 cols per block.
// B-fragments loaded directly from global (Wt is 64 KB, L2-resident).
__global__ __launch_bounds__(256) void k2b_mfma(
    const bf16* __restrict__ xg, const bf16* __restrict__ Wt,
    const float* __restrict__ cbev, bf16* __restrict__ e_val)
{
  __shared__ bf16 Xs[64][136];
  const int t = threadIdx.x;
  const int b = blockIdx.x / 127;
  const int rb = blockIdx.x - b*127;
  const int p0 = rb * 64;
  #pragma unroll
  for (int it = 0; it < 4; ++it){
    int idx = it*256 + t;
    int r = idx >> 4, seg = idx & 15;
    float4 xv = *reinterpret_cast<const float4*>(xg + (long)(b*PP + p0 + r)*HE + seg*8);
    *reinterpret_cast<float4*>(&Xs[r][seg*8]) = xv;
  }
  __syncthreads();
  const int wv = t>>6, lane = t&63;
  const int fm = lane & 15, q = lane >> 4;
  bf16x8 A[4];
  #pragma unroll
  for (int ks=0; ks<4; ++ks)
    A[ks] = *reinterpret_cast<const bf16x8*>(&Xs[wv*16 + fm][ks*32 + q*8]);
  #pragma unroll
  for (int ct=0; ct<16; ++ct){
    const int col = ct*16 + fm;
    float bb = cbev[col];
    f32x4 acc = {bb, bb, bb, bb};
    const bf16* wp = Wt + col*128 + q*8;
    #pragma unroll
    for (int ks=0; ks<4; ++ks){
      bf16x8 Bf = *reinterpret_cast<const bf16x8*>(wp + ks*32);
      acc = __builtin_amdgcn_mfma_f32_16x16x32_bf16(A[ks], Bf, acc, 0, 0, 0);
    }
    const int h = col >> 5, d = col & 31;
    bf16* op = e_val + ((long)(b*NH + h)*PP + p0 + wv*16 + q*4)*DH + d;
    #pragma unroll
    for (int reg=0; reg<4; ++reg) op[reg*DH] = __float2bfloat16(acc[reg]);
  }
}

// ---------------- Kernel 3: graph attention ----------------
// grid B*H*16 = 1024 blocks; block 256 (4 waves); 8 dest nodes/block, 2 iters
__global__ __launch_bounds__(256) void k3_attn(
    const float* __restrict__ q_ws, const float* __restrict__ k_ws, const float* __restrict__ v_ws,
    const bf16* __restrict__ e_val, const float* __restrict__ ea2,
    float* __restrict__ attn)
{
  __shared__ float kT[DH][NN+1];
  __shared__ float vS[NN][DH+1];
  __shared__ float qS[8][DH];
  __shared__ float pbuf[4][NN];
  const int t = threadIdx.x, wv = t>>6, lane = t&63;
  const int s16 = blockIdx.x & 15, h = (blockIdx.x>>4)&7, b = blockIdx.x>>7;
  const int bh = b*NH + h;
  const int n0 = s16*8;
  const float* kb = k_ws + (long)bh*NN*DH;
  const float* vb = v_ws + (long)bh*NN*DH;
  const float* qb = q_ws + ((long)bh*NN + n0)*DH;
  for (int idx=t; idx<NN*DH; idx+=256){
    int m = idx>>5, d = idx&31;
    kT[d][m] = kb[idx];
    vS[m][d] = vb[idx];
  }
  if (t < 8*DH) reinterpret_cast<float*>(qS)[t] = qb[t];
  __syncthreads();
  const float scale = 0.17677669529663687f;  // 32^-0.5
  const float* eab = ea2 + (long)bh*PP;
  const bf16* evp = e_val + (long)bh*PP*DH;
  for (int it=0; it<2; ++it){
    const int nn = it*4 + wv;
    const int n = n0 + nn;
    const int m1 = lane, m2 = lane + 64;
    float dot1 = 0.f, dot2 = 0.f;
    #pragma unroll
    for (int d=0; d<DH; d++){
      float qd = qS[nn][d];
      dot1 = fmaf(qd, kT[d][m1], dot1);
      dot2 = fmaf(qd, kT[d][m2], dot2);
    }
    const bool self1 = (m1 == n), self2 = (m2 == n);
    int pr1 = pair_idx(n, self1 ? (m1^1) : m1);
    int pr2 = pair_idx(n, self2 ? (m2^1) : m2);
    float ea1 = eab[pr1], ea2v = eab[pr2];
    float l1 = self1 ? -INFINITY : dot1*scale + ea1;
    float l2 = self2 ? -INFINITY : dot2*scale + ea2v;
    bool av = (!self1 && ea1 > -8.9e15f) || (!self2 && ea2v > -8.9e15f);
    float lm = wave_max(fmaxf(l1, l2));
    float e1 = __expf(l1 - lm), e2 = __expf(l2 - lm);
    float ssum = wave_sum(e1 + e2);
    int anyv = __any((int)av);
    float inv = anyv ? (1.0f/ssum) : 0.0f;
    pbuf[wv][m1] = e1*inv;
    pbuf[wv][m2] = e2*inv;
    // pbuf is per-wave private: same-wave LDS ordering, no barrier needed
    const int msub = lane & 15, oct = lane >> 4;
    float acc[8];
    #pragma unroll
    for (int e=0;e<8;e++) acc[e] = 0.f;
    #pragma unroll
    for (int mm=0; mm<128; mm+=16){
      int m = mm + msub;
      int ms = (m==n) ? (m^1) : m;
      int pr = pair_idx(n, ms);
      bf16x8 ev8 = *reinterpret_cast<const bf16x8*>(evp + (long)pr*DH + oct*8);
      float pm = pbuf[wv][m];
      const float* vrow = &vS[m][oct*8];
      #pragma unroll
      for (int e=0;e<8;e++){
        acc[e] = fmaf(pm, vrow[e] + bfraw2f(ev8[e]), acc[e]);
      }
    }
    #pragma unroll
    for (int off=1; off<16; off<<=1){
      #pragma unroll
      for (int e=0;e<8;e++) acc[e] += __shfl_xor(acc[e], off, 64);
    }
    if (msub == 0){
      float* op = attn + ((long)b*NN + n)*HN + h*DH + oct*8;
      float4 o0 = {acc[0],acc[1],acc[2],acc[3]};
      float4 o1 = {acc[4],acc[5],acc[6],acc[7]};
      *reinterpret_cast<float4*>(op) = o0;
      *reinterpret_cast<float4*>(op+4) = o1;
    }
  }
}

// ---------------- k45: Wo+GELU then Wsk+sigmoid gate, fused via LDS ----------------
__global__ __launch_bounds__(256) void k45_out(
    const float* __restrict__ nin_ws, const float* __restrict__ attn,
    const float* __restrict__ cWo, const float* __restrict__ cbo,
    const float* __restrict__ cWsk, const float* __restrict__ cbsk,
    const float* __restrict__ cnode, void* __restrict__ out,
    const int* __restrict__ flags)
{
  __shared__ float xc[4][2*HN];
  __shared__ float xc2[4][HN];
  const int t = threadIdx.x, wv = t>>6, lane = t&63;
  const int g0 = blockIdx.x*4;
  {
    int g = g0 + wv;
    #pragma unroll
    for (int i=0;i<4;i++){
      int c = lane + 64*i;
      xc[wv][c] = nin_ws[g*HN + c];
      xc[wv][HN + c] = attn[g*HN + c];
    }
  }
  __syncthreads();
  {
    float acc[4];
    float bb = cbo[t];
    #pragma unroll
    for (int r=0;r<4;r++) acc[r] = bb;
    for (int k=0;k<2*HN;k+=4){
      float4 xv[4];
      #pragma unroll
      for (int r=0;r<4;r++) xv[r] = *reinterpret_cast<const float4*>(&xc[r][k]);
      #pragma unroll
      for (int kk=0;kk<4;kk++){
        float w = cWo[(k+kk)*HN + t];
        #pragma unroll
        for (int r=0;r<4;r++) acc[r] = fmaf((&xv[r].x)[kk], w, acc[r]);
      }
    }
    #pragma unroll
    for (int r=0;r<4;r++){
      float x = acc[r];
      xc2[r][t] = 0.5f*x*(1.0f + erff(x*0.7071067811865475f));
    }
  }
  __syncthreads();
  const int f32 = flags[0];
  float accv[4], accg[4];
  float bv = cbsk[t], bg = cbsk[t+256];
  #pragma unroll
  for (int r=0;r<4;r++){ accv[r]=bv; accg[r]=bg; }
  for (int k=0;k<HN;k+=4){
    float4 xv[4];
    #pragma unroll
    for (int r=0;r<4;r++) xv[r] = *reinterpret_cast<const float4*>(&xc2[r][k]);
    #pragma unroll
    for (int kk=0;kk<4;kk++){
      float w0 = cWsk[(k+kk)*512 + t];
      float w1 = cWsk[(k+kk)*512 + t + 256];
      #pragma unroll
      for (int r=0;r<4;r++){
        float xr = (&xv[r].x)[kk];
        accv[r] = fmaf(xr, w0, accv[r]);
        accg[r] = fmaf(xr, w1, accg[r]);
      }
    }
  }
  #pragma unroll
  for (int r=0;r<4;r++){
    int g = g0 + r;
    float gg = 1.0f/(1.0f + __expf(-accg[r]));
    float nf = cnode[g*HN + t];
    float res = nf*(1.0f - gg) + accv[r]*gg;
    if (f32) ((float*)out)[g*HN + t] = res;
    else ((bf16*)out)[g*HN + t] = __float2bfloat16(res);
  }
}

extern "C" void kernel_launch(void* const* d_in, const int* in_sizes, int n_inputs,
                              void* d_out, int out_size, void* d_ws, size_t ws_size,
                              hipStream_t stream)
{
  float* ws = (float*)d_ws;
  float* c_node = ws + C_NODE;
  float* c_mask = ws + C_MASK;
  float* c_Wqkv = ws + C_WQKV;
  float* c_bqkv = ws + C_BQKV;
  float* c_bev  = ws + C_BEV;
  float* c_Wea  = ws + C_WEA;
  float* c_bea  = ws + C_BEA;
  float* c_Wo   = ws + C_WO;
  float* c_bo   = ws + C_BO;
  float* c_Wsk  = ws + C_WSK;
  float* c_bsk  = ws + C_BSK;
  float* c_gn   = ws + C_GN;
  float* c_bn   = ws + C_BN;
  float* c_ge   = ws + C_GE;
  float* c_be   = ws + C_BE;
  float* base   = ws + IOFF;
  float* nin_ws  = base + I_NIN;
  float* q_ws    = base + I_Q;
  float* k_ws    = base + I_K;
  float* v_ws    = base + I_V;
  float* attn_ws = base + I_ATTN;
  float* ea2_ws  = base + I_EA2;
  bf16*  xg_ws   = (bf16*)(base + I_XG);
  bf16*  eval_ws = (bf16*)(base + I_EVAL);
  bf16*  wt_ws   = (bf16*)(base + I_WT);
  int*   flags   = (int*)(base + I_FLG);

  SrcPtrs sp;
  sp.p[0]  = d_in[0];   // node_feat
  sp.p[1]  = d_in[4];   // mask_valid
  sp.p[2]  = d_in[5];   // Wqkv
  sp.p[3]  = d_in[6];   // bqkv
  sp.p[4]  = d_in[7];   // Wev
  sp.p[5]  = d_in[8];   // bev
  sp.p[6]  = d_in[9];   // Wea
  sp.p[7]  = d_in[10];  // bea
  sp.p[8]  = d_in[11];  // Wo
  sp.p[9]  = d_in[12];  // bo
  sp.p[10] = d_in[13];  // Wsk
  sp.p[11] = d_in[14];  // bsk
  sp.p[12] = d_in[15];  // gn
  sp.p[13] = d_in[16];  // bn
  sp.p[14] = d_in[17];  // ge
  sp.p[15] = d_in[18];  // be

  k_convert<<<CONVBLKS + 128, 256, 0, stream>>>(sp, ws, flags,
                                                (const unsigned short*)d_in[0],
                                                d_in[7], wt_ws);
  k1_node_ln_qkv<<<256, 256, 0, stream>>>(c_node, c_Wqkv, c_bqkv, c_gn, c_bn,
                                          nin_ws, q_ws, k_ws, v_ws);
  k2a_edge_ln<<<BP/16, 256, 0, stream>>>(d_in[1], c_Wea, c_bea, c_ge, c_be, c_mask,
                                         xg_ws, ea2_ws, flags);
  k2b_mfma<<<1016, 256, 0, stream>>>(xg_ws, wt_ws, c_bev, eval_ws);
  k3_attn<<<BB*NH*16, 256, 0, stream>>>(q_ws, k_ws, v_ws, eval_ws, ea2_ws, attn_ws);
  k45_out<<<256, 256, 0, stream>>>(nin_ws, attn_ws, c_Wo, c_bo, c_Wsk, c_bsk,
                                   c_node, d_out, flags);
}

// Round 6
// 235.825 us; speedup vs baseline: 1.0573x; 1.0573x over previous
//
#include <hip/hip_runtime.h>
#include <hip/hip_bf16.h>
#include <math.h>

#define BB 8
#define NN 128
#define HN 256
#define HE 128
#define NH 8
#define DH 32
#define PP 8128
#define BP (BB*PP)   // 65024

typedef __hip_bfloat16 bf16;
typedef __hip_bfloat162 bf162;
typedef __attribute__((ext_vector_type(8))) short bf16x8;
typedef __attribute__((ext_vector_type(4))) float f32x4;

__device__ __forceinline__ float bf2f(bf16 x){ return __bfloat162float(x); }
__device__ __forceinline__ float bfraw2f(short u){
  return __uint_as_float(((unsigned)(unsigned short)u) << 16);
}

__device__ __forceinline__ float wave_sum(float v){
  #pragma unroll
  for (int off=32; off>=1; off>>=1) v += __shfl_xor(v, off, 64);
  return v;
}
__device__ __forceinline__ float wave_max(float v){
  #pragma unroll
  for (int off=32; off>=1; off>>=1) v = fmaxf(v, __shfl_xor(v, off, 64));
  return v;
}
__device__ __forceinline__ float g16_sum(float v){
  #pragma unroll
  for (int off=8; off>=1; off>>=1) v += __shfl_xor(v, off, 16);
  return v;
}

// triu pair index for N=128, i<j: p = i*(255-i)/2 + (j-i-1)
__device__ __forceinline__ int pair_idx(int a, int c){
  int i = a < c ? a : c;
  int j = a < c ? c : a;
  return ((i*(255 - i))>>1) + (j - i - 1);
}

// ---- canonical fp32 workspace layout (float offsets). edge_feat NOT converted. ----
#define C_NODE 0LL
#define C_MASK 262144LL
#define C_WQKV 327168LL
#define C_BQKV 523776LL
#define C_WEV  524544LL
#define C_BEV  557312LL
#define C_WEA  557568LL
#define C_BEA  558592LL
#define C_WO   558600LL
#define C_BO   689672LL
#define C_WSK  689928LL
#define C_BSK  821000LL
#define C_GN   821512LL
#define C_BN   821768LL
#define C_GE   822024LL
#define C_BE   822152LL
#define IOFF   822400LL
#define TOT8   102785
#define CONVBLKS 402          // ceil(TOT8/256)
// intermediates (float offsets from IOFF)
#define I_NIN  0LL
#define I_Q    262144LL
#define I_K    524288LL
#define I_V    786432LL
#define I_ATTN 1048576LL
#define I_COMB 1310720LL
#define I_EA2  1572864LL   // [64][PP] f32 = 520192
#define I_XG   2093056LL   // [BP][128] bf16 = 4161536 float-slots
#define I_EVAL 6254592LL   // [64][PP][32] bf16 = 8323072 float-slots
#define I_WT   14577664LL  // [256][128] bf16 = 16384 float-slots
#define I_WOB  14594048LL  // [512][256] bf16 = 65536 float-slots
#define I_WSKB 14659584LL  // [256][512] bf16 = 65536 float-slots
#define I_FLG  14725120LL

// ---------------- Converter + Wev transpose + Wo/Wsk bf16 + dtype detect ----------
struct SrcPtrs { const void* p[16]; };

__global__ __launch_bounds__(256) void k_convert(SrcPtrs sp, float* __restrict__ dst,
                                                 int* __restrict__ flags,
                                                 const unsigned short* __restrict__ nodeRaw,
                                                 const void* __restrict__ rawWev,
                                                 bf16* __restrict__ Wt,
                                                 const void* __restrict__ rawWo,
                                                 const void* __restrict__ rawWsk,
                                                 bf16* __restrict__ WoB,
                                                 bf16* __restrict__ WskB)
{
  __shared__ int sbad;
  if (threadIdx.x == 0) sbad = 0;
  __syncthreads();
  {
    int bad = 0;
    for (int i = threadIdx.x; i < 1024; i += 256){
      unsigned e = (nodeRaw[i] >> 7) & 0xFFu;
      if (e >= 194u) bad = 1;
    }
    if (bad) sbad = 1;
  }
  __syncthreads();
  const int f32 = sbad;        // 1 = inputs fp32, 0 = bf16
  if (blockIdx.x == 0 && threadIdx.x == 0) flags[0] = f32;

  if (blockIdx.x >= CONVBLKS + 128){
    // Wo / Wsk -> bf16, same [k][n] layout. 32768 octets total.
    int o = (blockIdx.x - (CONVBLKS + 128))*256 + threadIdx.x;   // < 32768
    const void* src = (o < 16384) ? rawWo : rawWsk;
    bf16* dw = (o < 16384) ? WoB : WskB;
    int lo = (o < 16384) ? o : o - 16384;
    if (f32){
      const float4* s4 = (const float4*)src;
      float4 a0 = s4[2*lo], a1 = s4[2*lo+1];
      union { float4 f; bf16 h[8]; } cv;
      cv.h[0]=__float2bfloat16(a0.x); cv.h[1]=__float2bfloat16(a0.y);
      cv.h[2]=__float2bfloat16(a0.z); cv.h[3]=__float2bfloat16(a0.w);
      cv.h[4]=__float2bfloat16(a1.x); cv.h[5]=__float2bfloat16(a1.y);
      cv.h[6]=__float2bfloat16(a1.z); cv.h[7]=__float2bfloat16(a1.w);
      *reinterpret_cast<float4*>(dw + lo*8) = cv.f;
    } else {
      *reinterpret_cast<float4*>(dw + lo*8) = ((const float4*)src)[lo];  // bit-exact copy
    }
    return;
  }

  if (blockIdx.x >= CONVBLKS){
    // Wev transpose from RAW input: idx over [128][256] -> Wt [256][128] bf16
    int idx = (blockIdx.x - CONVBLKS)*256 + threadIdx.x;   // < 32768
    float v = f32 ? ((const float*)rawWev)[idx]
                  : bfraw2f(((const short*)rawWev)[idx]);
    Wt[(idx & 255)*128 + (idx >> 8)] = __float2bfloat16(v);
    return;
  }

  int o = blockIdx.x*256 + threadIdx.x;
  if (o >= TOT8) return;
  const int cum[17] = {0,32768,40896,65472,65568,69664,69696,69824,69825,
                       86209,86241,102625,102689,102721,102753,102769,102785};
  int s = 0;
  #pragma unroll
  for (int i = 1; i <= 15; i++) if (o >= cum[i]) s = i;
  const int li = o - cum[s];
  float4 r0, r1;
  if (f32){
    const float4* src = (const float4*)sp.p[s];
    r0 = src[2*li]; r1 = src[2*li+1];
  } else {
    union { float4 f; unsigned short u[8]; } cv;
    cv.f = ((const float4*)sp.p[s])[li];
    r0.x = __uint_as_float((unsigned)cv.u[0] << 16);
    r0.y = __uint_as_float((unsigned)cv.u[1] << 16);
    r0.z = __uint_as_float((unsigned)cv.u[2] << 16);
    r0.w = __uint_as_float((unsigned)cv.u[3] << 16);
    r1.x = __uint_as_float((unsigned)cv.u[4] << 16);
    r1.y = __uint_as_float((unsigned)cv.u[5] << 16);
    r1.z = __uint_as_float((unsigned)cv.u[6] << 16);
    r1.w = __uint_as_float((unsigned)cv.u[7] << 16);
  }
  float4* d = (float4*)(dst + (long long)cum[s]*8);
  d[2*li]   = r0;
  d[2*li+1] = r1;
}

// ---------------- Kernel 1: node LN + QKV GEMM ----------------
__global__ __launch_bounds__(256) void k1_node_ln_qkv(
    const float* __restrict__ cnode, const float* __restrict__ cWqkv,
    const float* __restrict__ cbqkv, const float* __restrict__ cgn, const float* __restrict__ cbn,
    float* __restrict__ nin_ws, float* __restrict__ q_ws, float* __restrict__ k_ws,
    float* __restrict__ v_ws)
{
  __shared__ float xln[4][HN];
  const int t = threadIdx.x, wv = t>>6, lane = t&63;
  const int g0 = blockIdx.x*4;
  {
    int g = g0 + wv;
    float x[4];
    #pragma unroll
    for (int i=0;i<4;i++) x[i] = cnode[g*HN + lane + 64*i];
    float s = x[0]+x[1]+x[2]+x[3];
    s = wave_sum(s);
    float m = s * (1.0f/HN);
    float q = 0.f;
    #pragma unroll
    for (int i=0;i<4;i++){ float d = x[i]-m; q += d*d; }
    q = wave_sum(q);
    float rstd = rsqrtf(fmaxf(q*(1.0f/HN), 0.f) + 1e-5f);
    #pragma unroll
    for (int i=0;i<4;i++){
      int c = lane + 64*i;
      float y = (x[i]-m)*rstd*cgn[c] + cbn[c];
      xln[wv][c] = y;
      nin_ws[g*HN + c] = y;
    }
  }
  __syncthreads();
  float acc[4][3];
  #pragma unroll
  for (int c=0;c<3;c++){
    float bb = cbqkv[t + 256*c];
    #pragma unroll
    for (int r=0;r<4;r++) acc[r][c] = bb;
  }
  for (int k=0;k<HN;k+=4){
    float4 xv[4];
    #pragma unroll
    for (int r=0;r<4;r++) xv[r] = *reinterpret_cast<const float4*>(&xln[r][k]);
    #pragma unroll
    for (int kk=0;kk<4;kk++){
      float w0 = cWqkv[(k+kk)*768 + t];
      float w1 = cWqkv[(k+kk)*768 + t + 256];
      float w2 = cWqkv[(k+kk)*768 + t + 512];
      #pragma unroll
      for (int r=0;r<4;r++){
        float xr = (&xv[r].x)[kk];
        acc[r][0] = fmaf(xr, w0, acc[r][0]);
        acc[r][1] = fmaf(xr, w1, acc[r][1]);
        acc[r][2] = fmaf(xr, w2, acc[r][2]);
      }
    }
  }
  const int h = t>>5, d = t&31;
  #pragma unroll
  for (int r=0;r<4;r++){
    int g = g0 + r;
    int b = g>>7, n = g&127;
    int o = ((b*NH + h)*NN + n)*DH + d;
    q_ws[o] = acc[r][0]; k_ws[o] = acc[r][1]; v_ws[o] = acc[r][2];
  }
}

// ---------------- k2a: edge LN -> xg (bf16), Wea GEMM + mask fold -> ea2 ----------
// grid 4064 (16 rows/block), block 256
__global__ __launch_bounds__(256) void k2a_edge_ln(
    const void* __restrict__ edge_raw, const float* __restrict__ cWea,
    const float* __restrict__ cbea, const float* __restrict__ cge,
    const float* __restrict__ cbe, const float* __restrict__ cmask,
    bf16* __restrict__ xg, float* __restrict__ ea2, const int* __restrict__ flags)
{
  __shared__ float xlnS[16][136];
  __shared__ float part[128];
  const int t = threadIdx.x;
  const int R0 = blockIdx.x*16;
  const int b = R0 / PP;
  const int p0 = R0 - b*PP;
  const int f32 = flags[0];
  {
    int r = t>>4, sub = t&15;
    long base = (long)(R0 + r)*HE + sub*8;
    float x[8];
    if (f32){
      const float* cef = (const float*)edge_raw + base;
      float4 a0 = *reinterpret_cast<const float4*>(cef);
      float4 a1 = *reinterpret_cast<const float4*>(cef + 4);
      x[0]=a0.x; x[1]=a0.y; x[2]=a0.z; x[3]=a0.w;
      x[4]=a1.x; x[5]=a1.y; x[6]=a1.z; x[7]=a1.w;
    } else {
      union { float4 f; short u[8]; } cv;
      cv.f = *reinterpret_cast<const float4*>((const bf16*)edge_raw + base);
      #pragma unroll
      for (int i=0;i<8;i++) x[i] = bfraw2f(cv.u[i]);
    }
    float s = 0.f;
    #pragma unroll
    for (int i=0;i<8;i++) s += x[i];
    s = g16_sum(s);
    float m = s*(1.0f/HE);
    float q = 0.f;
    #pragma unroll
    for (int i=0;i<8;i++){ float dd = x[i]-m; q += dd*dd; }
    q = g16_sum(q);
    float rstd = rsqrtf(fmaxf(q*(1.0f/HE), 0.f) + 1e-5f);
    #pragma unroll
    for (int i=0;i<8;i++){
      int c = sub*8 + i;
      xlnS[r][c] = (x[i]-m)*rstd*cge[c] + cbe[c];
    }
  }
  __syncthreads();
  // write xg: thread -> row = t>>4, 8 consecutive cols
  {
    int r = t>>4, c0 = (t&15)*8;
    union { float4 f; bf16 h[8]; } o;
    #pragma unroll
    for (int i=0;i<8;i++) o.h[i] = __float2bfloat16(xlnS[r][c0+i]);
    *reinterpret_cast<float4*>(xg + (long)(R0 + r)*HE + c0) = o.f;
  }
  // e_adj (+mask fold): all 256 threads; (r,c) with k-range split by half
  {
    const int c = t & 7, r = (t>>3) & 15, half = t>>7;
    const int pid = r*8 + c;
    float s = half ? 0.0f : cbea[c];
    const int k0 = half*64;
    #pragma unroll 8
    for (int k=k0; k<k0+64; k++) s = fmaf(xlnS[r][k], cWea[k*NH + c], s);
    if (half){ part[pid] = s; }
    __syncthreads();
    if (!half){
      s += part[pid];
      int p = p0 + r;
      float mk = cmask[b*PP + p];
      ea2[(b*NH + c)*PP + p] = (mk != 0.0f) ? s : -9e15f;
    }
  }
}

// ---------------- k2b: MFMA GEMM e_val = xg @ Wev + bev -> [b][h][p][32] bf16 ----
// grid 1016 = 8 b x 127 rowblocks; block 256. 64 rows x 256 cols per block.
__global__ __launch_bounds__(256) void k2b_mfma(
    const bf16* __restrict__ xg, const bf16* __restrict__ Wt,
    const float* __restrict__ cbev, bf16* __restrict__ e_val)
{
  __shared__ bf16 Xs[64][136];
  const int t = threadIdx.x;
  const int b = blockIdx.x / 127;
  const int rb = blockIdx.x - b*127;
  const int p0 = rb * 64;
  #pragma unroll
  for (int it = 0; it < 4; ++it){
    int idx = it*256 + t;
    int r = idx >> 4, seg = idx & 15;
    float4 xv = *reinterpret_cast<const float4*>(xg + (long)(b*PP + p0 + r)*HE + seg*8);
    *reinterpret_cast<float4*>(&Xs[r][seg*8]) = xv;
  }
  __syncthreads();
  const int wv = t>>6, lane = t&63;
  const int fm = lane & 15, q = lane >> 4;
  bf16x8 A[4];
  #pragma unroll
  for (int ks=0; ks<4; ++ks)
    A[ks] = *reinterpret_cast<const bf16x8*>(&Xs[wv*16 + fm][ks*32 + q*8]);
  #pragma unroll
  for (int ct=0; ct<16; ++ct){
    const int col = ct*16 + fm;
    float bb = cbev[col];
    f32x4 acc = {bb, bb, bb, bb};
    const bf16* wp = Wt + col*128 + q*8;
    #pragma unroll
    for (int ks=0; ks<4; ++ks){
      bf16x8 Bf = *reinterpret_cast<const bf16x8*>(wp + ks*32);
      acc = __builtin_amdgcn_mfma_f32_16x16x32_bf16(A[ks], Bf, acc, 0, 0, 0);
    }
    const int h = col >> 5, d = col & 31;
    bf16* op = e_val + ((long)(b*NH + h)*PP + p0 + wv*16 + q*4)*DH + d;
    #pragma unroll
    for (int reg=0; reg<4; ++reg) op[reg*DH] = __float2bfloat16(acc[reg]);
  }
}

// ---------------- Kernel 3: graph attention ----------------
// grid B*H*16 = 1024 blocks; block 256 (4 waves); 8 dest nodes/block, 2 iters
__global__ __launch_bounds__(256) void k3_attn(
    const float* __restrict__ q_ws, const float* __restrict__ k_ws, const float* __restrict__ v_ws,
    const bf16* __restrict__ e_val, const float* __restrict__ ea2,
    float* __restrict__ attn)
{
  __shared__ float kT[DH][NN+1];
  __shared__ float vS[NN][DH+1];
  __shared__ float qS[8][DH];
  __shared__ float pbuf[4][NN];
  const int t = threadIdx.x, wv = t>>6, lane = t&63;
  const int s16 = blockIdx.x & 15, h = (blockIdx.x>>4)&7, b = blockIdx.x>>7;
  const int bh = b*NH + h;
  const int n0 = s16*8;
  const float* kb = k_ws + (long)bh*NN*DH;
  const float* vb = v_ws + (long)bh*NN*DH;
  const float* qb = q_ws + ((long)bh*NN + n0)*DH;
  for (int idx=t; idx<NN*DH; idx+=256){
    int m = idx>>5, d = idx&31;
    kT[d][m] = kb[idx];
    vS[m][d] = vb[idx];
  }
  if (t < 8*DH) reinterpret_cast<float*>(qS)[t] = qb[t];
  __syncthreads();
  const float scale = 0.17677669529663687f;  // 32^-0.5
  const float* eab = ea2 + (long)bh*PP;
  const bf16* evp = e_val + (long)bh*PP*DH;
  for (int it=0; it<2; ++it){
    const int nn = it*4 + wv;
    const int n = n0 + nn;
    const int m1 = lane, m2 = lane + 64;
    float dot1 = 0.f, dot2 = 0.f;
    #pragma unroll
    for (int d=0; d<DH; d++){
      float qd = qS[nn][d];
      dot1 = fmaf(qd, kT[d][m1], dot1);
      dot2 = fmaf(qd, kT[d][m2], dot2);
    }
    const bool self1 = (m1 == n), self2 = (m2 == n);
    int pr1 = pair_idx(n, self1 ? (m1^1) : m1);
    int pr2 = pair_idx(n, self2 ? (m2^1) : m2);
    float ea1 = eab[pr1], ea2v = eab[pr2];
    float l1 = self1 ? -INFINITY : dot1*scale + ea1;
    float l2 = self2 ? -INFINITY : dot2*scale + ea2v;
    bool av = (!self1 && ea1 > -8.9e15f) || (!self2 && ea2v > -8.9e15f);
    float lm = wave_max(fmaxf(l1, l2));
    float e1 = __expf(l1 - lm), e2 = __expf(l2 - lm);
    float ssum = wave_sum(e1 + e2);
    int anyv = __any((int)av);
    float inv = anyv ? (1.0f/ssum) : 0.0f;
    pbuf[wv][m1] = e1*inv;
    pbuf[wv][m2] = e2*inv;
    // pbuf is per-wave private: same-wave LDS ordering, no barrier needed
    const int msub = lane & 15, oct = lane >> 4;
    float acc[8];
    #pragma unroll
    for (int e=0;e<8;e++) acc[e] = 0.f;
    #pragma unroll
    for (int mm=0; mm<128; mm+=16){
      int m = mm + msub;
      int ms = (m==n) ? (m^1) : m;
      int pr = pair_idx(n, ms);
      bf16x8 ev8 = *reinterpret_cast<const bf16x8*>(evp + (long)pr*DH + oct*8);
      float pm = pbuf[wv][m];
      const float* vrow = &vS[m][oct*8];
      #pragma unroll
      for (int e=0;e<8;e++){
        acc[e] = fmaf(pm, vrow[e] + bfraw2f(ev8[e]), acc[e]);
      }
    }
    #pragma unroll
    for (int off=1; off<16; off<<=1){
      #pragma unroll
      for (int e=0;e<8;e++) acc[e] += __shfl_xor(acc[e], off, 64);
    }
    if (msub == 0){
      float* op = attn + ((long)b*NN + n)*HN + h*DH + oct*8;
      float4 o0 = {acc[0],acc[1],acc[2],acc[3]};
      float4 o1 = {acc[4],acc[5],acc[6],acc[7]};
      *reinterpret_cast<float4*>(op) = o0;
      *reinterpret_cast<float4*>(op+4) = o1;
    }
  }
}

// ---------------- k4: concat(n_in, attn) @ Wo + bo, GELU ----------------
// grid 1024 = 256 rowgroups(4 rows) x 4 col-quarters(64); block 256 = 64 cols x 4 K-slices
__global__ __launch_bounds__(256) void k4_wo_gelu(
    const float* __restrict__ nin_ws, const float* __restrict__ attn,
    const bf16* __restrict__ WoB, const float* __restrict__ cbo,
    float* __restrict__ comb)
{
  __shared__ float xc[4][512];
  __shared__ float ps[3][4][64];
  const int t = threadIdx.x;
  const int g0 = (blockIdx.x >> 2) * 4;
  const int cq = blockIdx.x & 3;
  {
    int r = t>>6, c0 = (t&63)*8;
    const float* src = (c0 < 256) ? (nin_ws + (long)(g0+r)*HN + c0)
                                  : (attn + (long)(g0+r)*HN + (c0-256));
    float4 a0 = *reinterpret_cast<const float4*>(src);
    float4 a1 = *reinterpret_cast<const float4*>(src+4);
    *reinterpret_cast<float4*>(&xc[r][c0]) = a0;
    *reinterpret_cast<float4*>(&xc[r][c0+4]) = a1;
  }
  __syncthreads();
  const int cidx = t & 63, ks = t >> 6;
  const int col = cq*64 + cidx;
  float acc[4] = {0.f,0.f,0.f,0.f};
  const int k0 = ks*128;
  #pragma unroll 4
  for (int k=k0; k<k0+128; k++){
    float w = bf2f(WoB[k*HN + col]);
    #pragma unroll
    for (int r=0;r<4;r++) acc[r] = fmaf(xc[r][k], w, acc[r]);
  }
  if (ks){
    #pragma unroll
    for (int r=0;r<4;r++) ps[ks-1][r][cidx] = acc[r];
  }
  __syncthreads();
  if (!ks){
    float bb = cbo[col];
    #pragma unroll
    for (int r=0;r<4;r++){
      float x = acc[r] + bb + ps[0][r][cidx] + ps[1][r][cidx] + ps[2][r][cidx];
      comb[(long)(g0+r)*HN + col] = 0.5f*x*(1.0f + erff(x*0.7071067811865475f));
    }
  }
}

// ---------------- k5: comb @ Wsk + bsk, sigmoid gate + residual ----------------
// grid 1024 = 256 rowgroups(4 rows) x 4 col-quarters(64 val-cols); block 256 = 64 x 4 K-slices
__global__ __launch_bounds__(256) void k5_sk_gate(
    const float* __restrict__ comb, const float* __restrict__ cnode,
    const bf16* __restrict__ WskB, const float* __restrict__ cbsk,
    void* __restrict__ out, const int* __restrict__ flags)
{
  __shared__ float xc[4][HN];
  __shared__ float psv[3][4][64];
  __shared__ float psg[3][4][64];
  const int t = threadIdx.x;
  const int g0 = (blockIdx.x >> 2) * 4;
  const int cq = blockIdx.x & 3;
  {
    int r = t>>6, c0 = (t&63)*4;
    *reinterpret_cast<float4*>(&xc[r][c0]) =
        *reinterpret_cast<const float4*>(comb + (long)(g0+r)*HN + c0);
  }
  __syncthreads();
  const int cidx = t & 63, ks = t >> 6;
  const int col = cq*64 + cidx;
  float av[4] = {0.f,0.f,0.f,0.f}, ag[4] = {0.f,0.f,0.f,0.f};
  const int k0 = ks*64;
  #pragma unroll 4
  for (int k=k0; k<k0+64; k++){
    float wv = bf2f(WskB[k*512 + col]);
    float wg = bf2f(WskB[k*512 + col + 256]);
    #pragma unroll
    for (int r=0;r<4;r++){
      float xr = xc[r][k];
      av[r] = fmaf(xr, wv, av[r]);
      ag[r] = fmaf(xr, wg, ag[r]);
    }
  }
  if (ks){
    #pragma unroll
    for (int r=0;r<4;r++){ psv[ks-1][r][cidx] = av[r]; psg[ks-1][r][cidx] = ag[r]; }
  }
  __syncthreads();
  if (!ks){
    const int f32 = flags[0];
    float bv = cbsk[col], bg = cbsk[col+256];
    #pragma unroll
    for (int r=0;r<4;r++){
      float v = av[r] + bv + psv[0][r][cidx] + psv[1][r][cidx] + psv[2][r][cidx];
      float g = ag[r] + bg + psg[0][r][cidx] + psg[1][r][cidx] + psg[2][r][cidx];
      float gg = 1.0f/(1.0f + __expf(-g));
      float nf = cnode[(long)(g0+r)*HN + col];
      float res = nf*(1.0f - gg) + v*gg;
      if (f32) ((float*)out)[(long)(g0+r)*HN + col] = res;
      else ((bf16*)out)[(long)(g0+r)*HN + col] = __float2bfloat16(res);
    }
  }
}

extern "C" void kernel_launch(void* const* d_in, const int* in_sizes, int n_inputs,
                              void* d_out, int out_size, void* d_ws, size_t ws_size,
                              hipStream_t stream)
{
  float* ws = (float*)d_ws;
  float* c_node = ws + C_NODE;
  float* c_mask = ws + C_MASK;
  float* c_Wqkv = ws + C_WQKV;
  float* c_bqkv = ws + C_BQKV;
  float* c_bev  = ws + C_BEV;
  float* c_Wea  = ws + C_WEA;
  float* c_bea  = ws + C_BEA;
  float* c_bo   = ws + C_BO;
  float* c_bsk  = ws + C_BSK;
  float* c_gn   = ws + C_GN;
  float* c_bn   = ws + C_BN;
  float* c_ge   = ws + C_GE;
  float* c_be   = ws + C_BE;
  float* base   = ws + IOFF;
  float* nin_ws  = base + I_NIN;
  float* q_ws    = base + I_Q;
  float* k_ws    = base + I_K;
  float* v_ws    = base + I_V;
  float* attn_ws = base + I_ATTN;
  float* comb_ws = base + I_COMB;
  float* ea2_ws  = base + I_EA2;
  bf16*  xg_ws   = (bf16*)(base + I_XG);
  bf16*  eval_ws = (bf16*)(base + I_EVAL);
  bf16*  wt_ws   = (bf16*)(base + I_WT);
  bf16*  wob_ws  = (bf16*)(base + I_WOB);
  bf16*  wskb_ws = (bf16*)(base + I_WSKB);
  int*   flags   = (int*)(base + I_FLG);

  SrcPtrs sp;
  sp.p[0]  = d_in[0];   // node_feat
  sp.p[1]  = d_in[4];   // mask_valid
  sp.p[2]  = d_in[5];   // Wqkv
  sp.p[3]  = d_in[6];   // bqkv
  sp.p[4]  = d_in[7];   // Wev
  sp.p[5]  = d_in[8];   // bev
  sp.p[6]  = d_in[9];   // Wea
  sp.p[7]  = d_in[10];  // bea
  sp.p[8]  = d_in[11];  // Wo
  sp.p[9]  = d_in[12];  // bo
  sp.p[10] = d_in[13];  // Wsk
  sp.p[11] = d_in[14];  // bsk
  sp.p[12] = d_in[15];  // gn
  sp.p[13] = d_in[16];  // bn
  sp.p[14] = d_in[17];  // ge
  sp.p[15] = d_in[18];  // be

  k_convert<<<CONVBLKS + 256, 256, 0, stream>>>(sp, ws, flags,
                                                (const unsigned short*)d_in[0],
                                                d_in[7], wt_ws,
                                                d_in[11], d_in[13],
                                                wob_ws, wskb_ws);
  k1_node_ln_qkv<<<256, 256, 0, stream>>>(c_node, c_Wqkv, c_bqkv, c_gn, c_bn,
                                          nin_ws, q_ws, k_ws, v_ws);
  k2a_edge_ln<<<BP/16, 256, 0, stream>>>(d_in[1], c_Wea, c_bea, c_ge, c_be, c_mask,
                                         xg_ws, ea2_ws, flags);
  k2b_mfma<<<1016, 256, 0, stream>>>(xg_ws, wt_ws, c_bev, eval_ws);
  k3_attn<<<BB*NH*16, 256, 0, stream>>>(q_ws, k_ws, v_ws, eval_ws, ea2_ws, attn_ws);
  k4_wo_gelu<<<1024, 256, 0, stream>>>(nin_ws, attn_ws, wob_ws, c_bo, comb_ws);
  k5_sk_gate<<<1024, 256, 0, stream>>>(comb_ws, c_node, wskb_ws, c_bsk, d_out, flags);
}

// Round 7
// 199.215 us; speedup vs baseline: 1.2516x; 1.1838x over previous
//
#include <hip/hip_runtime.h>
#include <hip/hip_bf16.h>
#include <math.h>

#define BB 8
#define NN 128
#define HN 256
#define HE 128
#define NH 8
#define DH 32
#define PP 8128
#define BP (BB*PP)   // 65024

typedef __hip_bfloat16 bf16;
typedef __hip_bfloat162 bf162;
typedef __attribute__((ext_vector_type(8))) short bf16x8;
typedef __attribute__((ext_vector_type(4))) float f32x4;

__device__ __forceinline__ float bf2f(bf16 x){ return __bfloat162float(x); }
__device__ __forceinline__ float bfraw2f(short u){
  return __uint_as_float(((unsigned)(unsigned short)u) << 16);
}

__device__ __forceinline__ float wave_sum(float v){
  #pragma unroll
  for (int off=32; off>=1; off>>=1) v += __shfl_xor(v, off, 64);
  return v;
}
__device__ __forceinline__ float wave_max(float v){
  #pragma unroll
  for (int off=32; off>=1; off>>=1) v = fmaxf(v, __shfl_xor(v, off, 64));
  return v;
}
__device__ __forceinline__ float g16_sum(float v){
  #pragma unroll
  for (int off=8; off>=1; off>>=1) v += __shfl_xor(v, off, 16);
  return v;
}

// triu pair index for N=128, i<j: p = i*(255-i)/2 + (j-i-1)
__device__ __forceinline__ int pair_idx(int a, int c){
  int i = a < c ? a : c;
  int j = a < c ? c : a;
  return ((i*(255 - i))>>1) + (j - i - 1);
}

// ---- canonical fp32 workspace layout (float offsets). edge_feat NOT converted. ----
#define C_NODE 0LL
#define C_MASK 262144LL
#define C_WQKV 327168LL
#define C_BQKV 523776LL
#define C_WEV  524544LL
#define C_BEV  557312LL
#define C_WEA  557568LL
#define C_BEA  558592LL
#define C_WO   558600LL
#define C_BO   689672LL
#define C_WSK  689928LL
#define C_BSK  821000LL
#define C_GN   821512LL
#define C_BN   821768LL
#define C_GE   822024LL
#define C_BE   822152LL
#define IOFF   822400LL
#define TOT8   102785
#define CONVBLKS 402          // ceil(TOT8/256)
// intermediates (float offsets from IOFF)
#define I_NIN  0LL
#define I_Q    262144LL
#define I_K    524288LL
#define I_V    786432LL
#define I_ATTN 1048576LL
#define I_COMB 1310720LL
#define I_EA2  1572864LL   // [64][PP] f32 = 520192
#define I_XG   2093056LL   // [BP][128] bf16 = 4161536 float-slots
#define I_EVAL 6254592LL   // [64][PP][32] bf16 = 8323072 float-slots
#define I_WT   14577664LL  // [256][128] bf16 = 16384 float-slots
#define I_WOB  14594048LL  // [512][256] bf16 = 65536 float-slots
#define I_WSKB 14659584LL  // [256][512] bf16 = 65536 float-slots
#define I_FLG  14725120LL

// ---------------- Converter + Wev transpose + Wo/Wsk bf16 + dtype detect ----------
struct SrcPtrs { const void* p[16]; };

__global__ __launch_bounds__(256) void k_convert(SrcPtrs sp, float* __restrict__ dst,
                                                 int* __restrict__ flags,
                                                 const unsigned short* __restrict__ nodeRaw,
                                                 const void* __restrict__ rawWev,
                                                 bf16* __restrict__ Wt,
                                                 const void* __restrict__ rawWo,
                                                 const void* __restrict__ rawWsk,
                                                 bf16* __restrict__ WoB,
                                                 bf16* __restrict__ WskB)
{
  __shared__ int sbad;
  if (threadIdx.x == 0) sbad = 0;
  __syncthreads();
  {
    int bad = 0;
    for (int i = threadIdx.x; i < 1024; i += 256){
      unsigned e = (nodeRaw[i] >> 7) & 0xFFu;
      if (e >= 194u) bad = 1;
    }
    if (bad) sbad = 1;
  }
  __syncthreads();
  const int f32 = sbad;        // 1 = inputs fp32, 0 = bf16
  if (blockIdx.x == 0 && threadIdx.x == 0) flags[0] = f32;

  if (blockIdx.x >= CONVBLKS + 128){
    // Wo / Wsk -> bf16, same [k][n] layout. 32768 octets total.
    int o = (blockIdx.x - (CONVBLKS + 128))*256 + threadIdx.x;   // < 32768
    const void* src = (o < 16384) ? rawWo : rawWsk;
    bf16* dw = (o < 16384) ? WoB : WskB;
    int lo = (o < 16384) ? o : o - 16384;
    if (f32){
      const float4* s4 = (const float4*)src;
      float4 a0 = s4[2*lo], a1 = s4[2*lo+1];
      union { float4 f; bf16 h[8]; } cv;
      cv.h[0]=__float2bfloat16(a0.x); cv.h[1]=__float2bfloat16(a0.y);
      cv.h[2]=__float2bfloat16(a0.z); cv.h[3]=__float2bfloat16(a0.w);
      cv.h[4]=__float2bfloat16(a1.x); cv.h[5]=__float2bfloat16(a1.y);
      cv.h[6]=__float2bfloat16(a1.z); cv.h[7]=__float2bfloat16(a1.w);
      *reinterpret_cast<float4*>(dw + lo*8) = cv.f;
    } else {
      *reinterpret_cast<float4*>(dw + lo*8) = ((const float4*)src)[lo];  // bit-exact copy
    }
    return;
  }

  if (blockIdx.x >= CONVBLKS){
    // Wev transpose from RAW input: idx over [128][256] -> Wt [256][128] bf16
    int idx = (blockIdx.x - CONVBLKS)*256 + threadIdx.x;   // < 32768
    float v = f32 ? ((const float*)rawWev)[idx]
                  : bfraw2f(((const short*)rawWev)[idx]);
    Wt[(idx & 255)*128 + (idx >> 8)] = __float2bfloat16(v);
    return;
  }

  int o = blockIdx.x*256 + threadIdx.x;
  if (o >= TOT8) return;
  const int cum[17] = {0,32768,40896,65472,65568,69664,69696,69824,69825,
                       86209,86241,102625,102689,102721,102753,102769,102785};
  int s = 0;
  #pragma unroll
  for (int i = 1; i <= 15; i++) if (o >= cum[i]) s = i;
  const int li = o - cum[s];
  float4 r0, r1;
  if (f32){
    const float4* src = (const float4*)sp.p[s];
    r0 = src[2*li]; r1 = src[2*li+1];
  } else {
    union { float4 f; unsigned short u[8]; } cv;
    cv.f = ((const float4*)sp.p[s])[li];
    r0.x = __uint_as_float((unsigned)cv.u[0] << 16);
    r0.y = __uint_as_float((unsigned)cv.u[1] << 16);
    r0.z = __uint_as_float((unsigned)cv.u[2] << 16);
    r0.w = __uint_as_float((unsigned)cv.u[3] << 16);
    r1.x = __uint_as_float((unsigned)cv.u[4] << 16);
    r1.y = __uint_as_float((unsigned)cv.u[5] << 16);
    r1.z = __uint_as_float((unsigned)cv.u[6] << 16);
    r1.w = __uint_as_float((unsigned)cv.u[7] << 16);
  }
  float4* d = (float4*)(dst + (long long)cum[s]*8);
  d[2*li]   = r0;
  d[2*li+1] = r1;
}

// ---------------- Kernel 1: node LN + QKV GEMM, column-split x3 ----------------
// grid 768 = 256 rowgroups(4 rows) x 3 outputs {q,k,v}; block 256
__global__ __launch_bounds__(256) void k1_node_ln_qkv(
    const float* __restrict__ cnode, const float* __restrict__ cWqkv,
    const float* __restrict__ cbqkv, const float* __restrict__ cgn, const float* __restrict__ cbn,
    float* __restrict__ nin_ws, float* __restrict__ q_ws, float* __restrict__ k_ws,
    float* __restrict__ v_ws)
{
  __shared__ float xln[4][HN];
  const int t = threadIdx.x, wv = t>>6, lane = t&63;
  const int cb = blockIdx.x % 3;           // 0=q, 1=k, 2=v
  const int g0 = (blockIdx.x / 3) * 4;
  {
    int g = g0 + wv;
    float x[4];
    #pragma unroll
    for (int i=0;i<4;i++) x[i] = cnode[g*HN + lane + 64*i];
    float s = x[0]+x[1]+x[2]+x[3];
    s = wave_sum(s);
    float m = s * (1.0f/HN);
    float q = 0.f;
    #pragma unroll
    for (int i=0;i<4;i++){ float d = x[i]-m; q += d*d; }
    q = wave_sum(q);
    float rstd = rsqrtf(fmaxf(q*(1.0f/HN), 0.f) + 1e-5f);
    #pragma unroll
    for (int i=0;i<4;i++){
      int c = lane + 64*i;
      float y = (x[i]-m)*rstd*cgn[c] + cbn[c];
      xln[wv][c] = y;
      if (cb == 0) nin_ws[g*HN + c] = y;
    }
  }
  __syncthreads();
  const int col = cb*256 + t;
  float acc[4];
  {
    float bb = cbqkv[col];
    #pragma unroll
    for (int r=0;r<4;r++) acc[r] = bb;
  }
  for (int k=0;k<HN;k+=4){
    float4 xv[4];
    #pragma unroll
    for (int r=0;r<4;r++) xv[r] = *reinterpret_cast<const float4*>(&xln[r][k]);
    #pragma unroll
    for (int kk=0;kk<4;kk++){
      float w = cWqkv[(k+kk)*768 + col];
      #pragma unroll
      for (int r=0;r<4;r++) acc[r] = fmaf((&xv[r].x)[kk], w, acc[r]);
    }
  }
  float* dstp = (cb == 0) ? q_ws : (cb == 1) ? k_ws : v_ws;
  const int h = t>>5, d = t&31;
  #pragma unroll
  for (int r=0;r<4;r++){
    int g = g0 + r;
    int b = g>>7, n = g&127;
    dstp[((b*NH + h)*NN + n)*DH + d] = acc[r];
  }
}

// ---------------- k2a: edge LN -> xg (bf16), Wea GEMM + mask fold -> ea2 ----------
// grid 4064 (16 rows/block), block 256
__global__ __launch_bounds__(256) void k2a_edge_ln(
    const void* __restrict__ edge_raw, const float* __restrict__ cWea,
    const float* __restrict__ cbea, const float* __restrict__ cge,
    const float* __restrict__ cbe, const float* __restrict__ cmask,
    bf16* __restrict__ xg, float* __restrict__ ea2, const int* __restrict__ flags)
{
  __shared__ float xlnS[16][136];
  __shared__ float part[128];
  const int t = threadIdx.x;
  const int R0 = blockIdx.x*16;
  const int b = R0 / PP;
  const int p0 = R0 - b*PP;
  const int f32 = flags[0];
  {
    int r = t>>4, sub = t&15;
    long base = (long)(R0 + r)*HE + sub*8;
    float x[8];
    if (f32){
      const float* cef = (const float*)edge_raw + base;
      float4 a0 = *reinterpret_cast<const float4*>(cef);
      float4 a1 = *reinterpret_cast<const float4*>(cef + 4);
      x[0]=a0.x; x[1]=a0.y; x[2]=a0.z; x[3]=a0.w;
      x[4]=a1.x; x[5]=a1.y; x[6]=a1.z; x[7]=a1.w;
    } else {
      union { float4 f; short u[8]; } cv;
      cv.f = *reinterpret_cast<const float4*>((const bf16*)edge_raw + base);
      #pragma unroll
      for (int i=0;i<8;i++) x[i] = bfraw2f(cv.u[i]);
    }
    float s = 0.f;
    #pragma unroll
    for (int i=0;i<8;i++) s += x[i];
    s = g16_sum(s);
    float m = s*(1.0f/HE);
    float q = 0.f;
    #pragma unroll
    for (int i=0;i<8;i++){ float dd = x[i]-m; q += dd*dd; }
    q = g16_sum(q);
    float rstd = rsqrtf(fmaxf(q*(1.0f/HE), 0.f) + 1e-5f);
    #pragma unroll
    for (int i=0;i<8;i++){
      int c = sub*8 + i;
      xlnS[r][c] = (x[i]-m)*rstd*cge[c] + cbe[c];
    }
  }
  __syncthreads();
  // write xg: thread -> row = t>>4, 8 consecutive cols
  {
    int r = t>>4, c0 = (t&15)*8;
    union { float4 f; bf16 h[8]; } o;
    #pragma unroll
    for (int i=0;i<8;i++) o.h[i] = __float2bfloat16(xlnS[r][c0+i]);
    *reinterpret_cast<float4*>(xg + (long)(R0 + r)*HE + c0) = o.f;
  }
  // e_adj (+mask fold): all 256 threads; (r,c) with k-range split by half
  {
    const int c = t & 7, r = (t>>3) & 15, half = t>>7;
    const int pid = r*8 + c;
    float s = half ? 0.0f : cbea[c];
    const int k0 = half*64;
    #pragma unroll 8
    for (int k=k0; k<k0+64; k++) s = fmaf(xlnS[r][k], cWea[k*NH + c], s);
    if (half){ part[pid] = s; }
    __syncthreads();
    if (!half){
      s += part[pid];
      int p = p0 + r;
      float mk = cmask[b*PP + p];
      ea2[(b*NH + c)*PP + p] = (mk != 0.0f) ? s : -9e15f;
    }
  }
}

// ---------------- k2b: MFMA GEMM e_val = xg @ Wev + bev -> [b][h][p][32] bf16 ----
// grid 4064 = 1016 rowblocks x 4 colblocks, block 256 (round-4 v1 structure)
__global__ __launch_bounds__(256) void k2b_mfma(
    const bf16* __restrict__ xg, const bf16* __restrict__ Wt,
    const float* __restrict__ cbev, bf16* __restrict__ e_val)
{
  __shared__ bf16 Xs[64][136];
  __shared__ bf16 Ws[64][136];
  const int t = threadIdx.x;
  const int rowblk = blockIdx.x >> 2;
  const int cb = blockIdx.x & 3;
  const int b = rowblk / 127;
  const int p0 = (rowblk - b*127) * 64;
  const int n0 = cb * 64;
  #pragma unroll
  for (int it = 0; it < 4; ++it){
    int idx = it*256 + t;
    int r = idx >> 4, seg = idx & 15;
    float4 xv = *reinterpret_cast<const float4*>(xg + (long)(b*PP + p0 + r)*HE + seg*8);
    *reinterpret_cast<float4*>(&Xs[r][seg*8]) = xv;
    float4 wv = *reinterpret_cast<const float4*>(Wt + (long)(n0 + r)*HE + seg*8);
    *reinterpret_cast<float4*>(&Ws[r][seg*8]) = wv;
  }
  __syncthreads();
  const int wv = t>>6, lane = t&63;
  const int fm = lane & 15, q = lane >> 4;
  f32x4 acc[4];
  #pragma unroll
  for (int ct=0; ct<4; ++ct){
    float bb = cbev[n0 + ct*16 + fm];
    acc[ct][0]=bb; acc[ct][1]=bb; acc[ct][2]=bb; acc[ct][3]=bb;
  }
  #pragma unroll
  for (int ks=0; ks<4; ++ks){
    bf16x8 A = *reinterpret_cast<const bf16x8*>(&Xs[wv*16 + fm][ks*32 + q*8]);
    #pragma unroll
    for (int ct=0; ct<4; ++ct){
      bf16x8 Bf = *reinterpret_cast<const bf16x8*>(&Ws[ct*16 + fm][ks*32 + q*8]);
      acc[ct] = __builtin_amdgcn_mfma_f32_16x16x32_bf16(A, Bf, acc[ct], 0, 0, 0);
    }
  }
  #pragma unroll
  for (int ct=0; ct<4; ++ct){
    int col = n0 + ct*16 + fm;
    int h = col >> 5, d = col & 31;
    #pragma unroll
    for (int reg=0; reg<4; ++reg){
      int p = p0 + wv*16 + q*4 + reg;
      e_val[((long)(b*NH + h)*PP + p)*DH + d] = __float2bfloat16(acc[ct][reg]);
    }
  }
}

// ---------------- Kernel 3: graph attention ----------------
// grid B*H*16 = 1024 blocks; block 256 (4 waves); 8 dest nodes/block, 2 iters
__global__ __launch_bounds__(256) void k3_attn(
    const float* __restrict__ q_ws, const float* __restrict__ k_ws, const float* __restrict__ v_ws,
    const bf16* __restrict__ e_val, const float* __restrict__ ea2,
    float* __restrict__ attn)
{
  __shared__ float kT[DH][NN+1];
  __shared__ float vS[NN][DH+1];
  __shared__ float qS[8][DH];
  __shared__ float pbuf[4][NN];
  const int t = threadIdx.x, wv = t>>6, lane = t&63;
  const int s16 = blockIdx.x & 15, h = (blockIdx.x>>4)&7, b = blockIdx.x>>7;
  const int bh = b*NH + h;
  const int n0 = s16*8;
  const float* kb = k_ws + (long)bh*NN*DH;
  const float* vb = v_ws + (long)bh*NN*DH;
  const float* qb = q_ws + ((long)bh*NN + n0)*DH;
  for (int idx=t; idx<NN*DH; idx+=256){
    int m = idx>>5, d = idx&31;
    kT[d][m] = kb[idx];
    vS[m][d] = vb[idx];
  }
  if (t < 8*DH) reinterpret_cast<float*>(qS)[t] = qb[t];
  __syncthreads();
  const float scale = 0.17677669529663687f;  // 32^-0.5
  const float* eab = ea2 + (long)bh*PP;
  const bf16* evp = e_val + (long)bh*PP*DH;
  for (int it=0; it<2; ++it){
    const int nn = it*4 + wv;
    const int n = n0 + nn;
    const int m1 = lane, m2 = lane + 64;
    float dot1 = 0.f, dot2 = 0.f;
    #pragma unroll
    for (int d=0; d<DH; d++){
      float qd = qS[nn][d];
      dot1 = fmaf(qd, kT[d][m1], dot1);
      dot2 = fmaf(qd, kT[d][m2], dot2);
    }
    const bool self1 = (m1 == n), self2 = (m2 == n);
    int pr1 = pair_idx(n, self1 ? (m1^1) : m1);
    int pr2 = pair_idx(n, self2 ? (m2^1) : m2);
    float ea1 = eab[pr1], ea2v = eab[pr2];
    float l1 = self1 ? -INFINITY : dot1*scale + ea1;
    float l2 = self2 ? -INFINITY : dot2*scale + ea2v;
    bool av = (!self1 && ea1 > -8.9e15f) || (!self2 && ea2v > -8.9e15f);
    float lm = wave_max(fmaxf(l1, l2));
    float e1 = __expf(l1 - lm), e2 = __expf(l2 - lm);
    float ssum = wave_sum(e1 + e2);
    int anyv = __any((int)av);
    float inv = anyv ? (1.0f/ssum) : 0.0f;
    pbuf[wv][m1] = e1*inv;
    pbuf[wv][m2] = e2*inv;
    // pbuf is per-wave private: same-wave LDS ordering, no barrier needed
    const int msub = lane & 15, oct = lane >> 4;
    float acc[8];
    #pragma unroll
    for (int e=0;e<8;e++) acc[e] = 0.f;
    #pragma unroll
    for (int mm=0; mm<128; mm+=16){
      int m = mm + msub;
      int ms = (m==n) ? (m^1) : m;
      int pr = pair_idx(n, ms);
      bf16x8 ev8 = *reinterpret_cast<const bf16x8*>(evp + (long)pr*DH + oct*8);
      float pm = pbuf[wv][m];
      const float* vrow = &vS[m][oct*8];
      #pragma unroll
      for (int e=0;e<8;e++){
        acc[e] = fmaf(pm, vrow[e] + bfraw2f(ev8[e]), acc[e]);
      }
    }
    #pragma unroll
    for (int off=1; off<16; off<<=1){
      #pragma unroll
      for (int e=0;e<8;e++) acc[e] += __shfl_xor(acc[e], off, 64);
    }
    if (msub == 0){
      float* op = attn + ((long)b*NN + n)*HN + h*DH + oct*8;
      float4 o0 = {acc[0],acc[1],acc[2],acc[3]};
      float4 o1 = {acc[4],acc[5],acc[6],acc[7]};
      *reinterpret_cast<float4*>(op) = o0;
      *reinterpret_cast<float4*>(op+4) = o1;
    }
  }
}

// ---------------- k4: concat(n_in, attn) @ Wo + bo, GELU ----------------
// grid 1024 = 256 rowgroups(4 rows) x 4 col-quarters(64); block 256 = 64 cols x 4 K-slices
__global__ __launch_bounds__(256) void k4_wo_gelu(
    const float* __restrict__ nin_ws, const float* __restrict__ attn,
    const bf16* __restrict__ WoB, const float* __restrict__ cbo,
    float* __restrict__ comb)
{
  __shared__ float xc[4][512];
  __shared__ float ps[3][4][64];
  const int t = threadIdx.x;
  const int g0 = (blockIdx.x >> 2) * 4;
  const int cq = blockIdx.x & 3;
  {
    int r = t>>6, c0 = (t&63)*8;
    const float* src = (c0 < 256) ? (nin_ws + (long)(g0+r)*HN + c0)
                                  : (attn + (long)(g0+r)*HN + (c0-256));
    float4 a0 = *reinterpret_cast<const float4*>(src);
    float4 a1 = *reinterpret_cast<const float4*>(src+4);
    *reinterpret_cast<float4*>(&xc[r][c0]) = a0;
    *reinterpret_cast<float4*>(&xc[r][c0+4]) = a1;
  }
  __syncthreads();
  const int cidx = t & 63, ks = t >> 6;
  const int col = cq*64 + cidx;
  float acc[4] = {0.f,0.f,0.f,0.f};
  const int k0 = ks*128;
  #pragma unroll 4
  for (int k=k0; k<k0+128; k++){
    float w = bf2f(WoB[k*HN + col]);
    #pragma unroll
    for (int r=0;r<4;r++) acc[r] = fmaf(xc[r][k], w, acc[r]);
  }
  if (ks){
    #pragma unroll
    for (int r=0;r<4;r++) ps[ks-1][r][cidx] = acc[r];
  }
  __syncthreads();
  if (!ks){
    float bb = cbo[col];
    #pragma unroll
    for (int r=0;r<4;r++){
      float x = acc[r] + bb + ps[0][r][cidx] + ps[1][r][cidx] + ps[2][r][cidx];
      comb[(long)(g0+r)*HN + col] = 0.5f*x*(1.0f + erff(x*0.7071067811865475f));
    }
  }
}

// ---------------- k5: comb @ Wsk + bsk, sigmoid gate + residual ----------------
// grid 1024 = 256 rowgroups(4 rows) x 4 col-quarters(64 val-cols); block 256 = 64 x 4 K-slices
__global__ __launch_bounds__(256) void k5_sk_gate(
    const float* __restrict__ comb, const float* __restrict__ cnode,
    const bf16* __restrict__ WskB, const float* __restrict__ cbsk,
    void* __restrict__ out, const int* __restrict__ flags)
{
  __shared__ float xc[4][HN];
  __shared__ float psv[3][4][64];
  __shared__ float psg[3][4][64];
  const int t = threadIdx.x;
  const int g0 = (blockIdx.x >> 2) * 4;
  const int cq = blockIdx.x & 3;
  {
    int r = t>>6, c0 = (t&63)*4;
    *reinterpret_cast<float4*>(&xc[r][c0]) =
        *reinterpret_cast<const float4*>(comb + (long)(g0+r)*HN + c0);
  }
  __syncthreads();
  const int cidx = t & 63, ks = t >> 6;
  const int col = cq*64 + cidx;
  float av[4] = {0.f,0.f,0.f,0.f}, ag[4] = {0.f,0.f,0.f,0.f};
  const int k0 = ks*64;
  #pragma unroll 4
  for (int k=k0; k<k0+64; k++){
    float wv = bf2f(WskB[k*512 + col]);
    float wg = bf2f(WskB[k*512 + col + 256]);
    #pragma unroll
    for (int r=0;r<4;r++){
      float xr = xc[r][k];
      av[r] = fmaf(xr, wv, av[r]);
      ag[r] = fmaf(xr, wg, ag[r]);
    }
  }
  if (ks){
    #pragma unroll
    for (int r=0;r<4;r++){ psv[ks-1][r][cidx] = av[r]; psg[ks-1][r][cidx] = ag[r]; }
  }
  __syncthreads();
  if (!ks){
    const int f32 = flags[0];
    float bv = cbsk[col], bg = cbsk[col+256];
    #pragma unroll
    for (int r=0;r<4;r++){
      float v = av[r] + bv + psv[0][r][cidx] + psv[1][r][cidx] + psv[2][r][cidx];
      float g = ag[r] + bg + psg[0][r][cidx] + psg[1][r][cidx] + psg[2][r][cidx];
      float gg = 1.0f/(1.0f + __expf(-g));
      float nf = cnode[(long)(g0+r)*HN + col];
      float res = nf*(1.0f - gg) + v*gg;
      if (f32) ((float*)out)[(long)(g0+r)*HN + col] = res;
      else ((bf16*)out)[(long)(g0+r)*HN + col] = __float2bfloat16(res);
    }
  }
}

extern "C" void kernel_launch(void* const* d_in, const int* in_sizes, int n_inputs,
                              void* d_out, int out_size, void* d_ws, size_t ws_size,
                              hipStream_t stream)
{
  float* ws = (float*)d_ws;
  float* c_node = ws + C_NODE;
  float* c_mask = ws + C_MASK;
  float* c_Wqkv = ws + C_WQKV;
  float* c_bqkv = ws + C_BQKV;
  float* c_bev  = ws + C_BEV;
  float* c_Wea  = ws + C_WEA;
  float* c_bea  = ws + C_BEA;
  float* c_bo   = ws + C_BO;
  float* c_bsk  = ws + C_BSK;
  float* c_gn   = ws + C_GN;
  float* c_bn   = ws + C_BN;
  float* c_ge   = ws + C_GE;
  float* c_be   = ws + C_BE;
  float* base   = ws + IOFF;
  float* nin_ws  = base + I_NIN;
  float* q_ws    = base + I_Q;
  float* k_ws    = base + I_K;
  float* v_ws    = base + I_V;
  float* attn_ws = base + I_ATTN;
  float* comb_ws = base + I_COMB;
  float* ea2_ws  = base + I_EA2;
  bf16*  xg_ws   = (bf16*)(base + I_XG);
  bf16*  eval_ws = (bf16*)(base + I_EVAL);
  bf16*  wt_ws   = (bf16*)(base + I_WT);
  bf16*  wob_ws  = (bf16*)(base + I_WOB);
  bf16*  wskb_ws = (bf16*)(base + I_WSKB);
  int*   flags   = (int*)(base + I_FLG);

  SrcPtrs sp;
  sp.p[0]  = d_in[0];   // node_feat
  sp.p[1]  = d_in[4];   // mask_valid
  sp.p[2]  = d_in[5];   // Wqkv
  sp.p[3]  = d_in[6];   // bqkv
  sp.p[4]  = d_in[7];   // Wev
  sp.p[5]  = d_in[8];   // bev
  sp.p[6]  = d_in[9];   // Wea
  sp.p[7]  = d_in[10];  // bea
  sp.p[8]  = d_in[11];  // Wo
  sp.p[9]  = d_in[12];  // bo
  sp.p[10] = d_in[13];  // Wsk
  sp.p[11] = d_in[14];  // bsk
  sp.p[12] = d_in[15];  // gn
  sp.p[13] = d_in[16];  // bn
  sp.p[14] = d_in[17];  // ge
  sp.p[15] = d_in[18];  // be

  k_convert<<<CONVBLKS + 256, 256, 0, stream>>>(sp, ws, flags,
                                                (const unsigned short*)d_in[0],
                                                d_in[7], wt_ws,
                                                d_in[11], d_in[13],
                                                wob_ws, wskb_ws);
  k1_node_ln_qkv<<<768, 256, 0, stream>>>(c_node, c_Wqkv, c_bqkv, c_gn, c_bn,
                                          nin_ws, q_ws, k_ws, v_ws);
  k2a_edge_ln<<<BP/16, 256, 0, stream>>>(d_in[1], c_Wea, c_bea, c_ge, c_be, c_mask,
                                         xg_ws, ea2_ws, flags);
  k2b_mfma<<<4064, 256, 0, stream>>>(xg_ws, wt_ws, c_bev, eval_ws);
  k3_attn<<<BB*NH*16, 256, 0, stream>>>(q_ws, k_ws, v_ws, eval_ws, ea2_ws, attn_ws);
  k4_wo_gelu<<<1024, 256, 0, stream>>>(nin_ws, attn_ws, wob_ws, c_bo, comb_ws);
  k5_sk_gate<<<1024, 256, 0, stream>>>(comb_ws, c_node, wskb_ws, c_bsk, d_out, flags);
}